// Round 1
// baseline (790.064 us; speedup 1.0000x reference)
//
#include <hip/hip_runtime.h>
#include <hip/hip_bf16.h>
#include <stdint.h>
#include <math.h>

#define DIMC 2048
#define NH 16
#define HD 128
#define BBATCH 2
#define TSEQ 2048
#define MROWS (BBATCH*TSEQ)   // 4096
#define NQKV (3*DIMC)         // 6144

typedef __attribute__((ext_vector_type(8))) short short8;
typedef __attribute__((ext_vector_type(4))) float f32x4;

__device__ __forceinline__ short f2bf(float f) {
  union { float f; uint32_t u; } v; v.f = f;
  uint32_t r = (v.u + 0x7fffu + ((v.u >> 16) & 1u)) >> 16;
  return (short)(uint16_t)r;
}
__device__ __forceinline__ float bf2f(short s) {
  union { uint32_t u; float f; } v; v.u = ((uint32_t)(uint16_t)s) << 16;
  return v.f;
}
__device__ __forceinline__ void g2lds16(const void* g, void* l) {
  __builtin_amdgcn_global_load_lds((const __attribute__((address_space(1))) void*)g,
                                   (__attribute__((address_space(3))) void*)l, 16, 0, 0);
}

// ---------------- RoPE tables: cos/sin [T][64] ----------------
__global__ void rope_tables(float* __restrict__ cos_t, float* __restrict__ sin_t) {
  int idx = blockIdx.x * blockDim.x + threadIdx.x;   // T*64
  int t = idx >> 6, j = idx & 63;
  double inv = exp(-((double)(2 * j) / 128.0) * log(10000.0));
  float fr = (float)t * (float)inv;
  cos_t[idx] = cosf(fr);
  sin_t[idx] = sinf(fr);
}

// ---------------- fp32 -> bf16 cast (8 elems/thread) ----------------
__global__ void cast_f32_bf16(const float* __restrict__ in, short* __restrict__ out, int n8) {
  int i = blockIdx.x * blockDim.x + threadIdx.x;
  if (i >= n8) return;
  const float4* p = (const float4*)in;
  float4 a = p[2 * i], b = p[2 * i + 1];
  short8 o;
  o[0] = f2bf(a.x); o[1] = f2bf(a.y); o[2] = f2bf(a.z); o[3] = f2bf(a.w);
  o[4] = f2bf(b.x); o[5] = f2bf(b.y); o[6] = f2bf(b.z); o[7] = f2bf(b.w);
  ((short8*)out)[i] = o;
}

// ---------------- in-place RoPE on q,k [B,H,T,HD] bf16 ----------------
__global__ void rope_apply(short* __restrict__ q, short* __restrict__ k,
                           const float* __restrict__ cos_t, const float* __restrict__ sin_t) {
  int idx = blockIdx.x * blockDim.x + threadIdx.x;  // B*H*T*64
  int j = idx & 63;
  int t = (idx >> 6) & (TSEQ - 1);
  int bh = idx >> 17;
  size_t base = ((size_t)bh * TSEQ + t) * HD;
  float c = cos_t[t * 64 + j], s = sin_t[t * 64 + j];
  float x1 = bf2f(q[base + j]), x2 = bf2f(q[base + j + 64]);
  q[base + j]      = f2bf(x1 * c - x2 * s);
  q[base + j + 64] = f2bf(x2 * c + x1 * s);
  float y1 = bf2f(k[base + j]), y2 = bf2f(k[base + j + 64]);
  k[base + j]      = f2bf(y1 * c - y2 * s);
  k[base + j + 64] = f2bf(y2 * c + y1 * s);
}

// ---------------- GEMM C = A(bf16 MxK) * B(bf16 NxK)^T ----------------
// EPI 0: scatter to q/k/v bf16 [B,H,T,HD]   EPI 1: fp32 row-major Cout
template<int EPI>
__global__ __launch_bounds__(256)
void gemm_bt(const short* __restrict__ A, const short* __restrict__ B,
             int M, int N, int K,
             float* __restrict__ Cout,
             short* __restrict__ qp, short* __restrict__ kp, short* __restrict__ vp) {
  __shared__ short As[128 * 32];
  __shared__ short Bs[128 * 32];
  int tid = threadIdx.x;
  int lane = tid & 63, wave = tid >> 6;
  int wr = wave >> 1, wc = wave & 1;
  int bm = blockIdx.y, bn = blockIdx.x;
  int rowA0 = bm * 128, rowB0 = bn * 128;
  f32x4 acc[4][4] = {};
  for (int k0 = 0; k0 < K; k0 += 32) {
    #pragma unroll
    for (int j = 0; j < 2; ++j) {
      int c = tid + j * 256;           // 0..511 chunks of 16B
      int r = c >> 2, kk = (c & 3) * 8;
      g2lds16(A + (size_t)(rowA0 + r) * K + k0 + kk, As + c * 8);
      g2lds16(B + (size_t)(rowB0 + r) * K + k0 + kk, Bs + c * 8);
    }
    __syncthreads();
    short8 af[4], bfr[4];
    #pragma unroll
    for (int mf = 0; mf < 4; ++mf)
      af[mf] = *(const short8*)(As + (wr * 64 + mf * 16 + (lane & 15)) * 32 + 8 * (lane >> 4));
    #pragma unroll
    for (int nf = 0; nf < 4; ++nf)
      bfr[nf] = *(const short8*)(Bs + (wc * 64 + nf * 16 + (lane & 15)) * 32 + 8 * (lane >> 4));
    #pragma unroll
    for (int mf = 0; mf < 4; ++mf)
      #pragma unroll
      for (int nf = 0; nf < 4; ++nf)
        acc[mf][nf] = __builtin_amdgcn_mfma_f32_16x16x32_bf16(af[mf], bfr[nf], acc[mf][nf], 0, 0, 0);
    __syncthreads();
  }
  if (EPI == 1) {
    #pragma unroll
    for (int mf = 0; mf < 4; ++mf)
      #pragma unroll
      for (int nf = 0; nf < 4; ++nf)
        #pragma unroll
        for (int i = 0; i < 4; ++i) {
          int gm = rowA0 + wr * 64 + mf * 16 + ((lane >> 4) << 2) + i;
          int gn = rowB0 + wc * 64 + nf * 16 + (lane & 15);
          Cout[(size_t)gm * N + gn] = acc[mf][nf][i];
        }
  } else {
    short* dst = (bn < 16) ? qp : (bn < 32) ? kp : vp;
    int h = bn & 15;
    #pragma unroll
    for (int mf = 0; mf < 4; ++mf)
      #pragma unroll
      for (int nf = 0; nf < 4; ++nf)
        #pragma unroll
        for (int i = 0; i < 4; ++i) {
          int gm = rowA0 + wr * 64 + mf * 16 + ((lane >> 4) << 2) + i;
          int b = gm >> 11, t = gm & 2047;
          int d = wc * 64 + nf * 16 + (lane & 15);
          dst[(((size_t)b * NH + h) * TSEQ + t) * HD + d] = f2bf(acc[mf][nf][i]);
        }
  }
}

// ---------------- flash attention (causal), QBLK=64, KVBLK=64 ----------------
__global__ __launch_bounds__(256)
void flash_attn(const short* __restrict__ Q, const short* __restrict__ K,
                const short* __restrict__ V, short* __restrict__ Oout) {
  __shared__ short Ks[64 * 128];     // 16KB, linear
  __shared__ short Vt[128 * 72];     // transposed V, padded stride 72
  __shared__ short Pl[4 * 16 * 72];  // per-wave P, padded stride 72
  int tid = threadIdx.x, lane = tid & 63, wave = tid >> 6;
  int qt = blockIdx.x, h = blockIdx.y, b = blockIdx.z;
  size_t bh_off = ((size_t)b * NH + h) * TSEQ * HD;
  const short* Qp = Q + bh_off;
  const short* Kp = K + bh_off;
  const short* Vp = V + bh_off;
  int q0 = qt * 64 + wave * 16;
  short8 qf[4];
  #pragma unroll
  for (int ks = 0; ks < 4; ++ks)
    qf[ks] = *(const short8*)(Qp + (size_t)(q0 + (lane & 15)) * HD + ks * 32 + 8 * (lane >> 4));
  float m_run[4], l_run[4];
  f32x4 acc_o[8] = {};
  #pragma unroll
  for (int i = 0; i < 4; ++i) { m_run[i] = -INFINITY; l_run[i] = 0.f; }
  const float scale = 0.08838834764831845f;  // 1/sqrt(128)
  for (int it = 0; it <= qt; ++it) {
    int kv0 = it * 64;
    // stage K (64x128 linear)
    #pragma unroll
    for (int j = 0; j < 4; ++j) {
      int c = tid + j * 256;          // 0..1023 chunks
      int r = c >> 4, cc = c & 15;
      g2lds16(Kp + (size_t)(kv0 + r) * HD + cc * 8, Ks + c * 8);
    }
    // stage V transposed: Vt[d][kv], stride 72
    #pragma unroll
    for (int j = 0; j < 4; ++j) {
      int e = tid + j * 256;
      int r = e >> 4, c0 = (e & 15) * 8;
      short8 vv = *(const short8*)(Vp + (size_t)(kv0 + r) * HD + c0);
      #pragma unroll
      for (int jj = 0; jj < 8; ++jj)
        Vt[(c0 + jj) * 72 + r] = vv[jj];
    }
    __syncthreads();
    // S = Q K^T  (16 q-rows x 64 kv)
    f32x4 sa[4] = {};
    #pragma unroll
    for (int nf = 0; nf < 4; ++nf)
      #pragma unroll
      for (int ks = 0; ks < 4; ++ks) {
        short8 kf = *(const short8*)(Ks + (nf * 16 + (lane & 15)) * 128 + ks * 32 + 8 * (lane >> 4));
        sa[nf] = __builtin_amdgcn_mfma_f32_16x16x32_bf16(qf[ks], kf, sa[nf], 0, 0, 0);
      }
    bool lastTile = (it == qt);
    #pragma unroll
    for (int nf = 0; nf < 4; ++nf)
      #pragma unroll
      for (int i = 0; i < 4; ++i) {
        float s = sa[nf][i] * scale;
        if (lastTile) {
          int kvc = kv0 + nf * 16 + (lane & 15);
          int qr = q0 + ((lane >> 4) << 2) + i;
          if (kvc > qr) s = -INFINITY;
        }
        sa[nf][i] = s;
      }
    // online softmax per q-row
    #pragma unroll
    for (int i = 0; i < 4; ++i) {
      float t = fmaxf(fmaxf(sa[0][i], sa[1][i]), fmaxf(sa[2][i], sa[3][i]));
      t = fmaxf(t, __shfl_xor(t, 1));
      t = fmaxf(t, __shfl_xor(t, 2));
      t = fmaxf(t, __shfl_xor(t, 4));
      t = fmaxf(t, __shfl_xor(t, 8));
      float mn = fmaxf(m_run[i], t);
      float al = __expf(m_run[i] - mn);
      m_run[i] = mn;
      float su = 0.f;
      #pragma unroll
      for (int nf = 0; nf < 4; ++nf) {
        float p = __expf(sa[nf][i] - mn);
        sa[nf][i] = p;
        su += p;
      }
      su += __shfl_xor(su, 1);
      su += __shfl_xor(su, 2);
      su += __shfl_xor(su, 4);
      su += __shfl_xor(su, 8);
      l_run[i] = l_run[i] * al + su;
      #pragma unroll
      for (int nfd = 0; nfd < 8; ++nfd) acc_o[nfd][i] *= al;
    }
    // P -> LDS (per wave)
    short* Pw = Pl + wave * 16 * 72;
    #pragma unroll
    for (int nf = 0; nf < 4; ++nf)
      #pragma unroll
      for (int i = 0; i < 4; ++i)
        Pw[(((lane >> 4) << 2) + i) * 72 + nf * 16 + (lane & 15)] = f2bf(sa[nf][i]);
    // O += P V
    #pragma unroll
    for (int ks2 = 0; ks2 < 2; ++ks2) {
      short8 pf = *(const short8*)(Pw + (lane & 15) * 72 + ks2 * 32 + 8 * (lane >> 4));
      #pragma unroll
      for (int nfd = 0; nfd < 8; ++nfd) {
        short8 vf = *(const short8*)(Vt + (nfd * 16 + (lane & 15)) * 72 + ks2 * 32 + 8 * (lane >> 4));
        acc_o[nfd] = __builtin_amdgcn_mfma_f32_16x16x32_bf16(pf, vf, acc_o[nfd], 0, 0, 0);
      }
    }
    __syncthreads();
  }
  // epilogue: O /= l, write bf16 to attn_out [B,T,DIM]
  #pragma unroll
  for (int nfd = 0; nfd < 8; ++nfd)
    #pragma unroll
    for (int i = 0; i < 4; ++i) {
      int qr = q0 + ((lane >> 4) << 2) + i;
      int col = h * HD + nfd * 16 + (lane & 15);
      Oout[((size_t)b * TSEQ + qr) * DIMC + col] = f2bf(acc_o[nfd][i] / l_run[i]);
    }
}

extern "C" void kernel_launch(void* const* d_in, const int* in_sizes, int n_in,
                              void* d_out, int out_size, void* d_ws, size_t ws_size,
                              hipStream_t stream) {
  const float* x     = (const float*)d_in[0];
  const float* w_qkv = (const float*)d_in[1];
  const float* w_out = (const float*)d_in[2];
  float* out = (float*)d_out;
  char* ws = (char*)d_ws;
  size_t off = 0;
  auto alloc = [&](size_t bytes) {
    void* p = ws + off;
    off += (bytes + 255) & ~(size_t)255;
    return p;
  };
  float* cos_t = (float*)alloc((size_t)TSEQ * 64 * 4);
  float* sin_t = (float*)alloc((size_t)TSEQ * 64 * 4);
  short* xb    = (short*)alloc((size_t)MROWS * DIMC * 2);
  short* wqkvb = (short*)alloc((size_t)NQKV * DIMC * 2);
  short* woutb = (short*)alloc((size_t)DIMC * DIMC * 2);
  short* q     = (short*)alloc((size_t)BBATCH * NH * TSEQ * HD * 2);
  short* k     = (short*)alloc((size_t)BBATCH * NH * TSEQ * HD * 2);
  short* v     = (short*)alloc((size_t)BBATCH * NH * TSEQ * HD * 2);
  short* attn  = (short*)alloc((size_t)MROWS * DIMC * 2);

  rope_tables<<<(TSEQ * 64) / 256, 256, 0, stream>>>(cos_t, sin_t);
  cast_f32_bf16<<<(MROWS * DIMC / 8 + 255) / 256, 256, 0, stream>>>(x, xb, MROWS * DIMC / 8);
  cast_f32_bf16<<<(NQKV * DIMC / 8 + 255) / 256, 256, 0, stream>>>(w_qkv, wqkvb, NQKV * DIMC / 8);
  cast_f32_bf16<<<(DIMC * DIMC / 8 + 255) / 256, 256, 0, stream>>>(w_out, woutb, DIMC * DIMC / 8);

  gemm_bt<0><<<dim3(NQKV / 128, MROWS / 128), 256, 0, stream>>>(
      xb, wqkvb, MROWS, NQKV, DIMC, nullptr, q, k, v);

  rope_apply<<<(BBATCH * NH * TSEQ * 64) / 256, 256, 0, stream>>>(q, k, cos_t, sin_t);

  flash_attn<<<dim3(TSEQ / 64, NH, BBATCH), 256, 0, stream>>>(q, k, v, attn);

  gemm_bt<1><<<dim3(DIMC / 128, MROWS / 128), 256, 0, stream>>>(
      attn, woutb, MROWS, DIMC, DIMC, out, nullptr, nullptr, nullptr);
}

// Round 5
// 438.570 us; speedup vs baseline: 1.8015x; 1.8015x over previous
//
#include <hip/hip_runtime.h>
#include <hip/hip_bf16.h>
#include <stdint.h>
#include <math.h>

#define DIMC 2048
#define NH 16
#define HD 128
#define BBATCH 2
#define TSEQ 2048
#define MROWS (BBATCH*TSEQ)   // 4096
#define NQKV (3*DIMC)         // 6144

typedef __attribute__((ext_vector_type(8))) short short8;
typedef __attribute__((ext_vector_type(4))) float f32x4;

__device__ __forceinline__ short f2bf(float f) {
  union { float f; uint32_t u; } v; v.f = f;
  uint32_t r = (v.u + 0x7fffu + ((v.u >> 16) & 1u)) >> 16;
  return (short)(uint16_t)r;
}
__device__ __forceinline__ float bf2f(short s) {
  union { uint32_t u; float f; } v; v.u = ((uint32_t)(uint16_t)s) << 16;
  return v.f;
}
__device__ __forceinline__ void g2lds16(const void* g, void* l) {
  __builtin_amdgcn_global_load_lds((const __attribute__((address_space(1))) void*)g,
                                   (__attribute__((address_space(3))) void*)l, 16, 0, 0);
}

// ---------------- RoPE tables: cos/sin [T][64] ----------------
__global__ void rope_tables(float* __restrict__ cos_t, float* __restrict__ sin_t) {
  int idx = blockIdx.x * blockDim.x + threadIdx.x;   // T*64
  int t = idx >> 6, j = idx & 63;
  double inv = exp(-((double)(2 * j) / 128.0) * log(10000.0));
  float fr = (float)t * (float)inv;
  cos_t[idx] = cosf(fr);
  sin_t[idx] = sinf(fr);
}

// ---------------- fp32 -> bf16 cast (8 elems/thread) ----------------
__global__ void cast_f32_bf16(const float* __restrict__ in, short* __restrict__ out, int n8) {
  int i = blockIdx.x * blockDim.x + threadIdx.x;
  if (i >= n8) return;
  const float4* p = (const float4*)in;
  float4 a = p[2 * i], b = p[2 * i + 1];
  short8 o;
  o[0] = f2bf(a.x); o[1] = f2bf(a.y); o[2] = f2bf(a.z); o[3] = f2bf(a.w);
  o[4] = f2bf(b.x); o[5] = f2bf(b.y); o[6] = f2bf(b.z); o[7] = f2bf(b.w);
  ((short8*)out)[i] = o;
}

// ---------------- in-place RoPE on q,k [B,H,T,HD] bf16 ----------------
__global__ void rope_apply(short* __restrict__ q, short* __restrict__ k,
                           const float* __restrict__ cos_t, const float* __restrict__ sin_t) {
  int idx = blockIdx.x * blockDim.x + threadIdx.x;  // B*H*T*64
  int j = idx & 63;
  int t = (idx >> 6) & (TSEQ - 1);
  int bh = idx >> 17;
  size_t base = ((size_t)bh * TSEQ + t) * HD;
  float c = cos_t[t * 64 + j], s = sin_t[t * 64 + j];
  float x1 = bf2f(q[base + j]), x2 = bf2f(q[base + j + 64]);
  q[base + j]      = f2bf(x1 * c - x2 * s);
  q[base + j + 64] = f2bf(x2 * c + x1 * s);
  float y1 = bf2f(k[base + j]), y2 = bf2f(k[base + j + 64]);
  k[base + j]      = f2bf(y1 * c - y2 * s);
  k[base + j + 64] = f2bf(y2 * c + y1 * s);
}

// ---------------- GEMM C = A(bf16 MxK) * B(bf16 NxK)^T ----------------
// EPI 0: scatter to q/k/v bf16 [B,H,T,HD]   EPI 1: fp32 row-major Cout
template<int EPI>
__global__ __launch_bounds__(256)
void gemm_bt(const short* __restrict__ A, const short* __restrict__ B,
             int M, int N, int K,
             float* __restrict__ Cout,
             short* __restrict__ qp, short* __restrict__ kp, short* __restrict__ vp) {
  __shared__ short As[128 * 32];
  __shared__ short Bs[128 * 32];
  int tid = threadIdx.x;
  int lane = tid & 63, wave = tid >> 6;
  int wr = wave >> 1, wc = wave & 1;
  int bm = blockIdx.y, bn = blockIdx.x;
  int rowA0 = bm * 128, rowB0 = bn * 128;
  f32x4 acc[4][4] = {};
  for (int k0 = 0; k0 < K; k0 += 32) {
    #pragma unroll
    for (int j = 0; j < 2; ++j) {
      int c = tid + j * 256;           // 0..511 chunks of 16B
      int r = c >> 2, kk = (c & 3) * 8;
      g2lds16(A + (size_t)(rowA0 + r) * K + k0 + kk, As + c * 8);
      g2lds16(B + (size_t)(rowB0 + r) * K + k0 + kk, Bs + c * 8);
    }
    __syncthreads();
    short8 af[4], bfr[4];
    #pragma unroll
    for (int mf = 0; mf < 4; ++mf)
      af[mf] = *(const short8*)(As + (wr * 64 + mf * 16 + (lane & 15)) * 32 + 8 * (lane >> 4));
    #pragma unroll
    for (int nf = 0; nf < 4; ++nf)
      bfr[nf] = *(const short8*)(Bs + (wc * 64 + nf * 16 + (lane & 15)) * 32 + 8 * (lane >> 4));
    #pragma unroll
    for (int mf = 0; mf < 4; ++mf)
      #pragma unroll
      for (int nf = 0; nf < 4; ++nf)
        acc[mf][nf] = __builtin_amdgcn_mfma_f32_16x16x32_bf16(af[mf], bfr[nf], acc[mf][nf], 0, 0, 0);
    __syncthreads();
  }
  if (EPI == 1) {
    #pragma unroll
    for (int mf = 0; mf < 4; ++mf)
      #pragma unroll
      for (int nf = 0; nf < 4; ++nf)
        #pragma unroll
        for (int i = 0; i < 4; ++i) {
          int gm = rowA0 + wr * 64 + mf * 16 + ((lane >> 4) << 2) + i;
          int gn = rowB0 + wc * 64 + nf * 16 + (lane & 15);
          Cout[(size_t)gm * N + gn] = acc[mf][nf][i];
        }
  } else {
    short* dst = (bn < 16) ? qp : (bn < 32) ? kp : vp;
    int h = bn & 15;
    #pragma unroll
    for (int mf = 0; mf < 4; ++mf)
      #pragma unroll
      for (int nf = 0; nf < 4; ++nf)
        #pragma unroll
        for (int i = 0; i < 4; ++i) {
          int gm = rowA0 + wr * 64 + mf * 16 + ((lane >> 4) << 2) + i;
          int b = gm >> 11, t = gm & 2047;
          int d = wc * 64 + nf * 16 + (lane & 15);
          dst[(((size_t)b * NH + h) * TSEQ + t) * HD + d] = f2bf(acc[mf][nf][i]);
        }
  }
}

// ---------------- flash attention (causal), QBLK=64, KVBLK=64 ----------------
// LDS swizzles (all bijective chunk-XOR within rows; rule #21 both-sides):
//  Ks : phys(row,k)  = row*128 + ((k>>3 ^ (row&7))<<3) + (k&7)     [staged via pre-swizzled g2lds src]
//  Vt : phys(d,kv)   = d*64 + ((kv>>3 ^ (d&7) ^ ((d>>3)&7))<<3) + (kv&7)
//  Pl : phys(q,kv)   = q*64 + ((kv>>3 ^ (q&7))<<3) + (kv&7)
__global__ __launch_bounds__(256)
void flash_attn(const short* __restrict__ Q, const short* __restrict__ K,
                const short* __restrict__ V, short* __restrict__ Oout) {
  __shared__ short Ks[64 * 128];     // 16KB
  __shared__ short Vt[128 * 64];     // 16KB transposed V, swizzled
  __shared__ short Pl[4 * 16 * 64];  // 8KB per-wave P, swizzled
  int tid = threadIdx.x, lane = tid & 63, wave = tid >> 6;
  // heavy-first dispatch: qt descending across bid; same (b,h) sticks to one XCD
  int bid = blockIdx.x;
  int qt = (TSEQ / 64 - 1) - (bid >> 5);
  int hb = bid & 31;
  int h = hb & 15, b = hb >> 4;
  size_t bh_off = ((size_t)b * NH + h) * TSEQ * HD;
  const short* Qp = Q + bh_off;
  const short* Kp = K + bh_off;
  const short* Vp = V + bh_off;
  int q0 = qt * 64 + wave * 16;
  short8 qf[4];
  #pragma unroll
  for (int ks = 0; ks < 4; ++ks)
    qf[ks] = *(const short8*)(Qp + (size_t)(q0 + (lane & 15)) * HD + ks * 32 + 8 * (lane >> 4));
  float m_run[4], l_run[4];
  f32x4 acc_o[8] = {};
  #pragma unroll
  for (int i = 0; i < 4; ++i) { m_run[i] = -INFINITY; l_run[i] = 0.f; }
  const float scale = 0.08838834764831845f;  // 1/sqrt(128)
  for (int it = 0; it <= qt; ++it) {
    int kv0 = it * 64;
    // V tile -> regs (issue first; latency hides under K staging)
    short8 vv[4];
    #pragma unroll
    for (int j = 0; j < 4; ++j) {
      int e = tid + j * 256;
      int r = e >> 4, c0 = (e & 15) * 8;
      vv[j] = *(const short8*)(Vp + (size_t)(kv0 + r) * HD + c0);
    }
    // stage K (64x128), pre-swizzled source chunk so swizzled read is linear-dest-safe
    #pragma unroll
    for (int j = 0; j < 4; ++j) {
      int c = tid + j * 256;          // physical 16B chunk index
      int r = c >> 4, cc = c & 15;
      g2lds16(Kp + (size_t)(kv0 + r) * HD + ((cc ^ (r & 7)) << 3), Ks + c * 8);
    }
    // scatter V transpose into swizzled Vt
    #pragma unroll
    for (int j = 0; j < 4; ++j) {
      int e = tid + j * 256;
      int r = e >> 4, c0 = (e & 15) * 8;
      int rc = r >> 3, rl = r & 7;
      #pragma unroll
      for (int jj = 0; jj < 8; ++jj) {
        int d = c0 + jj;
        int pch = rc ^ (d & 7) ^ ((d >> 3) & 7);
        Vt[d * 64 + (pch << 3) + rl] = vv[j][jj];
      }
    }
    __syncthreads();
    // S = Q K^T  (16 q-rows x 64 kv)
    f32x4 sa[4] = {};
    __builtin_amdgcn_s_setprio(1);
    #pragma unroll
    for (int nf = 0; nf < 4; ++nf)
      #pragma unroll
      for (int ks = 0; ks < 4; ++ks) {
        int row = nf * 16 + (lane & 15);
        int lch = ks * 4 + (lane >> 4);
        short8 kf = *(const short8*)(Ks + row * 128 + ((lch ^ (row & 7)) << 3));
        sa[nf] = __builtin_amdgcn_mfma_f32_16x16x32_bf16(qf[ks], kf, sa[nf], 0, 0, 0);
      }
    __builtin_amdgcn_s_setprio(0);
    bool lastTile = (it == qt);
    #pragma unroll
    for (int nf = 0; nf < 4; ++nf)
      #pragma unroll
      for (int i = 0; i < 4; ++i) {
        float s = sa[nf][i] * scale;
        if (lastTile) {
          int kvc = kv0 + nf * 16 + (lane & 15);
          int qr = q0 + ((lane >> 4) << 2) + i;
          if (kvc > qr) s = -INFINITY;
        }
        sa[nf][i] = s;
      }
    // online softmax per q-row (rows live across 16 lanes)
    #pragma unroll
    for (int i = 0; i < 4; ++i) {
      float t = fmaxf(fmaxf(sa[0][i], sa[1][i]), fmaxf(sa[2][i], sa[3][i]));
      t = fmaxf(t, __shfl_xor(t, 1));
      t = fmaxf(t, __shfl_xor(t, 2));
      t = fmaxf(t, __shfl_xor(t, 4));
      t = fmaxf(t, __shfl_xor(t, 8));
      float mn = fmaxf(m_run[i], t);
      float al = __expf(m_run[i] - mn);
      m_run[i] = mn;
      float su = 0.f;
      #pragma unroll
      for (int nf = 0; nf < 4; ++nf) {
        float p = __expf(sa[nf][i] - mn);
        sa[nf][i] = p;
        su += p;
      }
      su += __shfl_xor(su, 1);
      su += __shfl_xor(su, 2);
      su += __shfl_xor(su, 4);
      su += __shfl_xor(su, 8);
      l_run[i] = l_run[i] * al + su;
      #pragma unroll
      for (int nfd = 0; nfd < 8; ++nfd) acc_o[nfd][i] *= al;
    }
    // P -> LDS (per wave, swizzled)
    short* Pw = Pl + wave * 16 * 64;
    #pragma unroll
    for (int nf = 0; nf < 4; ++nf)
      #pragma unroll
      for (int i = 0; i < 4; ++i) {
        int qq = ((lane >> 4) << 2) + i;
        int kv = nf * 16 + (lane & 15);
        Pw[qq * 64 + (((kv >> 3) ^ (qq & 7)) << 3) + (kv & 7)] = f2bf(sa[nf][i]);
      }
    // O += P V
    __builtin_amdgcn_s_setprio(1);
    #pragma unroll
    for (int ks2 = 0; ks2 < 2; ++ks2) {
      int qq = lane & 15;
      int lchp = ks2 * 4 + (lane >> 4);
      short8 pf = *(const short8*)(Pw + qq * 64 + ((lchp ^ (qq & 7)) << 3));
      #pragma unroll
      for (int nfd = 0; nfd < 8; ++nfd) {
        int d = nfd * 16 + (lane & 15);
        int lch = ks2 * 4 + (lane >> 4);
        int pch = lch ^ (d & 7) ^ ((d >> 3) & 7);
        short8 vf = *(const short8*)(Vt + d * 64 + (pch << 3));
        acc_o[nfd] = __builtin_amdgcn_mfma_f32_16x16x32_bf16(pf, vf, acc_o[nfd], 0, 0, 0);
      }
    }
    __builtin_amdgcn_s_setprio(0);
    __syncthreads();
  }
  // epilogue: O /= l, write bf16 to attn_out [B,T,DIM]
  #pragma unroll
  for (int nfd = 0; nfd < 8; ++nfd)
    #pragma unroll
    for (int i = 0; i < 4; ++i) {
      int qr = q0 + ((lane >> 4) << 2) + i;
      int col = h * HD + nfd * 16 + (lane & 15);
      Oout[((size_t)b * TSEQ + qr) * DIMC + col] = f2bf(acc_o[nfd][i] / l_run[i]);
    }
}

extern "C" void kernel_launch(void* const* d_in, const int* in_sizes, int n_in,
                              void* d_out, int out_size, void* d_ws, size_t ws_size,
                              hipStream_t stream) {
  const float* x     = (const float*)d_in[0];
  const float* w_qkv = (const float*)d_in[1];
  const float* w_out = (const float*)d_in[2];
  float* out = (float*)d_out;
  char* ws = (char*)d_ws;
  size_t off = 0;
  auto alloc = [&](size_t bytes) {
    void* p = ws + off;
    off += (bytes + 255) & ~(size_t)255;
    return p;
  };
  float* cos_t = (float*)alloc((size_t)TSEQ * 64 * 4);
  float* sin_t = (float*)alloc((size_t)TSEQ * 64 * 4);
  short* xb    = (short*)alloc((size_t)MROWS * DIMC * 2);
  short* wqkvb = (short*)alloc((size_t)NQKV * DIMC * 2);
  short* woutb = (short*)alloc((size_t)DIMC * DIMC * 2);
  short* q     = (short*)alloc((size_t)BBATCH * NH * TSEQ * HD * 2);
  short* k     = (short*)alloc((size_t)BBATCH * NH * TSEQ * HD * 2);
  short* v     = (short*)alloc((size_t)BBATCH * NH * TSEQ * HD * 2);
  short* attn  = (short*)alloc((size_t)MROWS * DIMC * 2);

  rope_tables<<<(TSEQ * 64) / 256, 256, 0, stream>>>(cos_t, sin_t);
  cast_f32_bf16<<<(MROWS * DIMC / 8 + 255) / 256, 256, 0, stream>>>(x, xb, MROWS * DIMC / 8);
  cast_f32_bf16<<<(NQKV * DIMC / 8 + 255) / 256, 256, 0, stream>>>(w_qkv, wqkvb, NQKV * DIMC / 8);
  cast_f32_bf16<<<(DIMC * DIMC / 8 + 255) / 256, 256, 0, stream>>>(w_out, woutb, DIMC * DIMC / 8);

  gemm_bt<0><<<dim3(NQKV / 128, MROWS / 128), 256, 0, stream>>>(
      xb, wqkvb, MROWS, NQKV, DIMC, nullptr, q, k, v);

  rope_apply<<<(BBATCH * NH * TSEQ * 64) / 256, 256, 0, stream>>>(q, k, cos_t, sin_t);

  flash_attn<<<dim3((TSEQ / 64) * NH * BBATCH), 256, 0, stream>>>(q, k, v, attn);

  gemm_bt<1><<<dim3(DIMC / 128, MROWS / 128), 256, 0, stream>>>(
      attn, woutb, MROWS, DIMC, DIMC, out, nullptr, nullptr, nullptr);
}